// Round 7
// baseline (86.931 us; speedup 1.0000x reference)
//
#include <hip/hip_runtime.h>
#include <math.h>

#define NPRED 16384
#define NGT   32768
#define BETA  0.45f
#define GAMMA 0.45f

#define BLOCK 256
#define PPT   8                                // preds per thread (16 spilled: R6)
#define PRED_PER_BLOCK (BLOCK * PPT)           // 2048
#define PRED_CHUNKS (NPRED / PRED_PER_BLOCK)   // 8
#define SLAB  256                              // gt rows per block
#define NSLAB (NGT / SLAB)                     // 128

typedef __attribute__((ext_vector_type(16))) float f32x16;

// ---------------------------------------------------------------------------
// prep: h[j] = (-2gx,-2gy,-2gz,|g|^2), linear float4 layout for SMEM streaming.
// ---------------------------------------------------------------------------
__global__ __launch_bounds__(BLOCK) void prep_kernel(
    const float* __restrict__ gt_data, float4* __restrict__ h)
{
    const int j = blockIdx.x * BLOCK + threadIdx.x;
    if (j < NGT) {
        const float x = gt_data[j * 6 + 0];
        const float y = gt_data[j * 6 + 1];
        const float z = gt_data[j * 6 + 2];
        h[j] = make_float4(-2.0f * x, -2.0f * y, -2.0f * z,
                           fmaf(x, x, fmaf(y, y, z * z)));
    }
}

// ---------------------------------------------------------------------------
// nn: gt rows live in SGPRs via s_load_dwordx16 (4 rows / load, scalar cache,
// zero VALU+LDS cost). v_fma takes the SGPR operand directly (1 sgpr/instr).
// Double-buffered, strict alternation (SMEM returns OOO -> only lgkmcnt(0);
// each drain covers the single outstanding load). 3.5 VALU ops/pair.
// Cross-slab merge: u64 atomicMin on sortable(dmin)<<32 | slab_id.
// ---------------------------------------------------------------------------
__global__ __launch_bounds__(BLOCK) void nn_kernel(
    const float* __restrict__ pred_feat,
    const float4* __restrict__ hglob,
    unsigned long long* __restrict__ packed)
{
    const int chunk   = blockIdx.x;
    const int slab    = blockIdx.y;
    const int gt_base = slab * SLAB;
    const int t       = threadIdx.x;

    float px[PPT], py[PPT], pz[PPT], kmin[PPT];
    const int pred_base = chunk * PRED_PER_BLOCK + t;
#pragma unroll
    for (int p = 0; p < PPT; ++p) {
        const int i = pred_base + p * BLOCK;
        px[p] = pred_feat[i * 6 + 0];
        py[p] = pred_feat[i * 6 + 1];
        pz[p] = pred_feat[i * 6 + 2];
        kmin[p] = 1e30f;
    }

    // rows r0,r0+1 of tuple V (V holds 4 rows: 16 floats)
#define PAIR(V, r0)                                                           \
    _Pragma("unroll")                                                         \
    for (int p = 0; p < PPT; ++p) {                                           \
        const float d0 = fmaf(px[p], V[4*(r0)+0], fmaf(py[p], V[4*(r0)+1],    \
                              fmaf(pz[p], V[4*(r0)+2], V[4*(r0)+3])));        \
        const float d1 = fmaf(px[p], V[4*(r0)+4], fmaf(py[p], V[4*(r0)+5],    \
                              fmaf(pz[p], V[4*(r0)+6], V[4*(r0)+7])));        \
        asm("v_min3_f32 %0, %0, %1, %2" : "+v"(kmin[p]) : "v"(d0), "v"(d1));  \
    }
#define COMPUTE4(V) PAIR(V, 0) PAIR(V, 2)

    const float* hp = (const float*)(hglob + gt_base);
    f32x16 A, B;
    asm volatile("s_load_dwordx16 %0, %1, 0x0" : "=s"(A) : "s"(hp));

#pragma unroll 1
    for (int j = 0; j < SLAB; j += 8) {
        asm volatile("s_waitcnt lgkmcnt(0)" : "+s"(A));          // A ready
        asm volatile("s_load_dwordx16 %0, %1, 0x40" : "=s"(B) : "s"(hp));
        COMPUTE4(A)                                              // rows j..j+3
        asm volatile("s_waitcnt lgkmcnt(0)" : "+s"(B));          // B ready
        if (j + 8 < SLAB) {
            hp += 32;                                            // 8 rows = 128 B
            asm volatile("s_load_dwordx16 %0, %1, 0x0" : "=s"(A) : "s"(hp));
        }
        COMPUTE4(B)                                              // rows j+4..j+7
    }
#undef COMPUTE4
#undef PAIR

#pragma unroll
    for (int p = 0; p < PPT; ++p) {
        const int i = pred_base + p * BLOCK;
        const unsigned int bits = __float_as_uint(kmin[p]);
        const unsigned int key  = (bits & 0x80000000u) ? ~bits : (bits | 0x80000000u);
        const unsigned long long pk =
            ((unsigned long long)key << 32) | (unsigned int)slab;
        atomicMin(&packed[i], pk);
    }
}

// ---------------------------------------------------------------------------
// rescan + finalize, wave-cooperative (R6, unchanged): one wave per pred,
// coalesced slab scan, first match via ballot+ffsll = first-j semantics.
// ---------------------------------------------------------------------------
#define RES_PREDS_PER_WAVE 4
#define RES_PREDS_PER_BLOCK (4 * RES_PREDS_PER_WAVE)   // 16
#define RES_BLOCKS (NPRED / RES_PREDS_PER_BLOCK)       // 1024

__global__ __launch_bounds__(BLOCK) void rescan_kernel(
    const float* __restrict__ pred_feat,
    const float* __restrict__ gt_data,
    const float4* __restrict__ hglob,
    const float* __restrict__ Rm,
    const float* __restrict__ tv,
    const float* __restrict__ sv,
    const unsigned long long* __restrict__ packed,
    float* __restrict__ out)
{
    __shared__ float wsum[4];
    const int wave = threadIdx.x >> 6;
    const int lane = threadIdx.x & 63;

    float csum = 0.0f;
#pragma unroll
    for (int q = 0; q < RES_PREDS_PER_WAVE; ++q) {
        const int i = blockIdx.x * RES_PREDS_PER_BLOCK + wave * RES_PREDS_PER_WAVE + q;

        const unsigned long long pk = packed[i];
        const unsigned int key  = (unsigned int)(pk >> 32);
        const unsigned int slab = (unsigned int)(pk & 0xFFFFFFFFu);
        const unsigned int tbits = (key & 0x80000000u) ? (key ^ 0x80000000u) : ~key;
        const int gt_base = (int)slab * SLAB;

        const float px = pred_feat[i * 6 + 0];
        const float py = pred_feat[i * 6 + 1];
        const float pz = pred_feat[i * 6 + 2];

        int jfound = 0;
        bool done = false;
#pragma unroll
        for (int k = 0; k < SLAB / 64; ++k) {
            const float4 g = hglob[gt_base + k * 64 + lane];
            const float d = fmaf(px, g.x, fmaf(py, g.y, fmaf(pz, g.z, g.w)));
            const unsigned long long m = __ballot(__float_as_uint(d) == tbits);
            if (!done && m) {
                jfound = k * 64 + (__ffsll((unsigned long long)m) - 1);
                done = true;
            }
        }
        const int idx = gt_base + jfound;

        if (lane == 0) {
            const float nx = pred_feat[i * 6 + 3];
            const float ny = pred_feat[i * 6 + 4];
            const float nz = pred_feat[i * 6 + 5];
            const float gx = gt_data[idx * 6 + 3];
            const float gy = gt_data[idx * 6 + 4];
            const float gz = gt_data[idx * 6 + 5];
            const float pn = fmaxf(sqrtf(fmaf(nx, nx, fmaf(ny, ny, nz * nz))), 1e-12f);
            const float gn = fmaxf(sqrtf(fmaf(gx, gx, fmaf(gy, gy, gz * gz))), 1e-12f);
            const float cosv = fmaf(nx, gx, fmaf(ny, gy, nz * gz)) / (pn * gn);
            csum += 1.0f - cosv;
        }
    }

    if (lane == 0) wsum[wave] = csum;
    __syncthreads();

    if (threadIdx.x == 0) {
        float s = wsum[0] + wsum[1] + wsum[2] + wsum[3];
        atomicAdd(out, s * (GAMMA / (float)NPRED));
        if (blockIdx.x == 0) {
            float rs = 0.0f;
#pragma unroll
            for (int k = 0; k < 9; ++k) {
                const float v = Rm[k] - ((k % 4 == 0) ? 1.0f : 0.0f);
                rs = fmaf(v, v, rs);
            }
            const float rot = sqrtf(rs);
            const float tr  = sqrtf(fmaf(tv[0], tv[0], fmaf(tv[1], tv[1], tv[2] * tv[2])));
            const float sc  = (sv[0] - 1.0f) * (sv[0] - 1.0f);
            atomicAdd(out, BETA * (rot + tr + sc));
        }
    }
}

extern "C" void kernel_launch(void* const* d_in, const int* in_sizes, int n_in,
                              void* d_out, int out_size, void* d_ws, size_t ws_size,
                              hipStream_t stream)
{
    const float* pred = (const float*)d_in[0];
    const float* gt   = (const float*)d_in[1];
    const float* Rm   = (const float*)d_in[2];
    const float* tv   = (const float*)d_in[3];
    const float* sv   = (const float*)d_in[4];
    float* out = (float*)d_out;

    unsigned long long* packed = (unsigned long long*)d_ws;                      // 128 KB
    float4* hglob = (float4*)((char*)d_ws + NPRED * sizeof(unsigned long long)); // 512 KB

    hipMemsetAsync(packed, 0xFF, NPRED * sizeof(unsigned long long), stream);
    hipMemsetAsync(out, 0, sizeof(float), stream);

    prep_kernel<<<NGT / BLOCK, BLOCK, 0, stream>>>(gt, hglob);
    dim3 grid(PRED_CHUNKS, NSLAB);
    nn_kernel<<<grid, BLOCK, 0, stream>>>(pred, hglob, packed);
    rescan_kernel<<<RES_BLOCKS, BLOCK, 0, stream>>>(pred, gt, hglob, Rm, tv, sv,
                                                    packed, out);
}

// Round 8
// 73.051 us; speedup vs baseline: 1.1900x; 1.1900x over previous
//
#include <hip/hip_runtime.h>
#include <math.h>

#define NPRED 16384
#define NGT   32768
#define BETA  0.45f
#define GAMMA 0.45f

#define BLOCK 256
#define PPT   16                               // preds per thread
#define PRED_PER_BLOCK (BLOCK * PPT)           // 4096
#define PRED_CHUNKS (NPRED / PRED_PER_BLOCK)   // 4
#define SLAB  256                              // gt rows per block (== BLOCK)
#define NSLAB (NGT / SLAB)                     // 128

// ---------------------------------------------------------------------------
// nn: min-distance only, 3.5 VALU ops/pair (3 fma + 0.5 v_min3_f32).
//   LDS h = (-2gx,-2gy,-2gz,|g|^2);  d = fma(px,hx,fma(py,hy,fma(pz,hz,hw)))
//   PPT=16 amortizes each ds_read_b128 broadcast over 112 VALU instrs
//   (DS pipe ~43% of the VALU window, vs 86% at PPT=8).
//   __launch_bounds__(256,2) -> up to 256 VGPR: the 64-reg pred arrays fit
//   (R6's PPT=16 spilled at the default budget: VGPR_Count=44 < 64 needed).
// Cross-slab merge: u64 atomicMin on sortable(dmin) << 32 | slab_id
//   (ties -> lower slab = smaller global index; rescan takes first j).
// chunk==0 blocks also write h to global for the rescan pass.
// ---------------------------------------------------------------------------
__global__ __launch_bounds__(BLOCK, 2) void nn_kernel(
    const float* __restrict__ pred_feat,
    const float* __restrict__ gt_data,
    unsigned long long* __restrict__ packed,
    float4* __restrict__ hglob)
{
    __shared__ float4 hs[SLAB + 2];

    const int chunk   = blockIdx.x;
    const int slab    = blockIdx.y;
    const int gt_base = slab * SLAB;
    const int t       = threadIdx.x;

    {
        const int gj = gt_base + t;
        const float x = gt_data[gj * 6 + 0];
        const float y = gt_data[gj * 6 + 1];
        const float z = gt_data[gj * 6 + 2];
        const float4 h = make_float4(-2.0f * x, -2.0f * y, -2.0f * z,
                                     fmaf(x, x, fmaf(y, y, z * z)));
        hs[t] = h;
        if (chunk == 0) hglob[gj] = h;
        if (t < 2) hs[SLAB + t] = make_float4(0.0f, 0.0f, 0.0f, 1e30f); // pad
    }
    __syncthreads();

    float px[PPT], py[PPT], pz[PPT], kmin[PPT];
    const int pred_base = chunk * PRED_PER_BLOCK + t;
#pragma unroll
    for (int p = 0; p < PPT; ++p) {
        const int i = pred_base + p * BLOCK;
        px[p] = pred_feat[i * 6 + 0];
        py[p] = pred_feat[i * 6 + 1];
        pz[p] = pred_feat[i * 6 + 2];
        kmin[p] = 1e30f;
    }

#define STEP(G0, G1)                                                          \
    _Pragma("unroll")                                                         \
    for (int p = 0; p < PPT; ++p) {                                           \
        const float d0 = fmaf(px[p], G0.x, fmaf(py[p], G0.y,                  \
                              fmaf(pz[p], G0.z, G0.w)));                      \
        const float d1 = fmaf(px[p], G1.x, fmaf(py[p], G1.y,                  \
                              fmaf(pz[p], G1.z, G1.w)));                      \
        asm("v_min3_f32 %0, %0, %1, %2" : "+v"(kmin[p]) : "v"(d0), "v"(d1));  \
    }

    float4 a0 = hs[0], a1 = hs[1], b0, b1;
#pragma unroll 1
    for (int j = 0; j < SLAB; j += 4) {
        b0 = hs[j + 2]; b1 = hs[j + 3];
        STEP(a0, a1)
        a0 = hs[j + 4]; a1 = hs[j + 5];   // last iter reads pad rows (unused)
        STEP(b0, b1)
    }
#undef STEP

#pragma unroll
    for (int p = 0; p < PPT; ++p) {
        const int i = pred_base + p * BLOCK;
        const unsigned int bits = __float_as_uint(kmin[p]);
        const unsigned int key  = (bits & 0x80000000u) ? ~bits : (bits | 0x80000000u);
        const unsigned long long pk =
            ((unsigned long long)key << 32) | (unsigned int)slab;
        atomicMin(&packed[i], pk);
    }
}

// ---------------------------------------------------------------------------
// rescan + finalize, wave-cooperative: one wave scans one pred's winning slab
// (lanes read rows k*64+lane -> coalesced; hglob is L2-resident). First match
// in ascending k via ballot+ffsll = first-j semantics (bit-identical fmaf
// chain to nn). Each wave handles 4 preds; one atomicAdd per block.
// ---------------------------------------------------------------------------
#define RES_PREDS_PER_WAVE 4
#define RES_PREDS_PER_BLOCK (4 * RES_PREDS_PER_WAVE)   // 16
#define RES_BLOCKS (NPRED / RES_PREDS_PER_BLOCK)       // 1024

__global__ __launch_bounds__(BLOCK) void rescan_kernel(
    const float* __restrict__ pred_feat,
    const float* __restrict__ gt_data,
    const float4* __restrict__ hglob,
    const float* __restrict__ Rm,
    const float* __restrict__ tv,
    const float* __restrict__ sv,
    const unsigned long long* __restrict__ packed,
    float* __restrict__ out)
{
    __shared__ float wsum[4];
    const int wave = threadIdx.x >> 6;
    const int lane = threadIdx.x & 63;

    float csum = 0.0f;
#pragma unroll
    for (int q = 0; q < RES_PREDS_PER_WAVE; ++q) {
        const int i = blockIdx.x * RES_PREDS_PER_BLOCK + wave * RES_PREDS_PER_WAVE + q;

        const unsigned long long pk = packed[i];
        const unsigned int key  = (unsigned int)(pk >> 32);
        const unsigned int slab = (unsigned int)(pk & 0xFFFFFFFFu);
        const unsigned int tbits = (key & 0x80000000u) ? (key ^ 0x80000000u) : ~key;
        const int gt_base = (int)slab * SLAB;

        const float px = pred_feat[i * 6 + 0];
        const float py = pred_feat[i * 6 + 1];
        const float pz = pred_feat[i * 6 + 2];

        int jfound = 0;
        bool done = false;
#pragma unroll
        for (int k = 0; k < SLAB / 64; ++k) {
            const float4 g = hglob[gt_base + k * 64 + lane];
            const float d = fmaf(px, g.x, fmaf(py, g.y, fmaf(pz, g.z, g.w)));
            const unsigned long long m = __ballot(__float_as_uint(d) == tbits);
            if (!done && m) {
                jfound = k * 64 + (__ffsll((unsigned long long)m) - 1);
                done = true;
            }
        }
        const int idx = gt_base + jfound;

        if (lane == 0) {
            const float nx = pred_feat[i * 6 + 3];
            const float ny = pred_feat[i * 6 + 4];
            const float nz = pred_feat[i * 6 + 5];
            const float gx = gt_data[idx * 6 + 3];
            const float gy = gt_data[idx * 6 + 4];
            const float gz = gt_data[idx * 6 + 5];
            const float pn = fmaxf(sqrtf(fmaf(nx, nx, fmaf(ny, ny, nz * nz))), 1e-12f);
            const float gn = fmaxf(sqrtf(fmaf(gx, gx, fmaf(gy, gy, gz * gz))), 1e-12f);
            const float cosv = fmaf(nx, gx, fmaf(ny, gy, nz * gz)) / (pn * gn);
            csum += 1.0f - cosv;
        }
    }

    if (lane == 0) wsum[wave] = csum;
    __syncthreads();

    if (threadIdx.x == 0) {
        float s = wsum[0] + wsum[1] + wsum[2] + wsum[3];
        atomicAdd(out, s * (GAMMA / (float)NPRED));
        if (blockIdx.x == 0) {
            float rs = 0.0f;
#pragma unroll
            for (int k = 0; k < 9; ++k) {
                const float v = Rm[k] - ((k % 4 == 0) ? 1.0f : 0.0f);
                rs = fmaf(v, v, rs);
            }
            const float rot = sqrtf(rs);
            const float tr  = sqrtf(fmaf(tv[0], tv[0], fmaf(tv[1], tv[1], tv[2] * tv[2])));
            const float sc  = (sv[0] - 1.0f) * (sv[0] - 1.0f);
            atomicAdd(out, BETA * (rot + tr + sc));
        }
    }
}

extern "C" void kernel_launch(void* const* d_in, const int* in_sizes, int n_in,
                              void* d_out, int out_size, void* d_ws, size_t ws_size,
                              hipStream_t stream)
{
    const float* pred = (const float*)d_in[0];
    const float* gt   = (const float*)d_in[1];
    const float* Rm   = (const float*)d_in[2];
    const float* tv   = (const float*)d_in[3];
    const float* sv   = (const float*)d_in[4];
    float* out = (float*)d_out;

    unsigned long long* packed = (unsigned long long*)d_ws;                      // 128 KB
    float4* hglob = (float4*)((char*)d_ws + NPRED * sizeof(unsigned long long)); // 512 KB

    hipMemsetAsync(packed, 0xFF, NPRED * sizeof(unsigned long long), stream);
    hipMemsetAsync(out, 0, sizeof(float), stream);

    dim3 grid(PRED_CHUNKS, NSLAB);
    nn_kernel<<<grid, BLOCK, 0, stream>>>(pred, gt, packed, hglob);
    rescan_kernel<<<RES_BLOCKS, BLOCK, 0, stream>>>(pred, gt, hglob, Rm, tv, sv,
                                                    packed, out);
}